// Round 1
// baseline (7297.728 us; speedup 1.0000x reference)
//
#include <hip/hip_runtime.h>
#include <cmath>
#include <cstddef>

// ---------------------------------------------------------------------------
// SMILModel: masked VAE branch (2048 rows) + full classifier (4096 rows).
// Round 1: correctness-first fp32 tiled SGEMM with fused epilogues.
// B=4096 D=4096 H=4096 O=1000 P=2048; mask = mm%2==1 -> 2048 masked rows.
// ---------------------------------------------------------------------------

// Stable binary argsort of mask: perm = [rows with mask=0 in order, rows with
// mask=1 in order]. Single block, 1024 threads, 4 elements each, LDS scan.
__global__ __launch_bounds__(1024)
void perm_kernel(const int* __restrict__ mm, int* __restrict__ perm)
{
    __shared__ int sdata[1024];
    const int t = threadIdx.x;
    int m[4];
    int cnt = 0;
#pragma unroll
    for (int j = 0; j < 4; ++j) {
        int i = t * 4 + j;
        m[j] = mm[i] & 1;
        cnt += m[j];
    }
    sdata[t] = cnt;
    __syncthreads();
    // Hillis-Steele inclusive scan over the 1024 per-thread counts.
    for (int off = 1; off < 1024; off <<= 1) {
        int v = (t >= off) ? sdata[t - off] : 0;
        __syncthreads();
        sdata[t] += v;
        __syncthreads();
    }
    const int total_ones = sdata[1023];
    const int n0 = 4096 - total_ones;
    int ones_before  = sdata[t] - cnt;       // exclusive prefix of ones
    int zeros_before = t * 4 - ones_before;  // exclusive prefix of zeros
#pragma unroll
    for (int j = 0; j < 4; ++j) {
        int i = t * 4 + j;
        if (m[j]) perm[n0 + (ones_before++)] = i;
        else      perm[(zeros_before++)]     = i;
    }
}

// Builds (a) top half of permuted `combined` = x[even rows] and
// (b) x_m = x[masked rows] (contiguous input for the VAE branch).
// grid (4, 4096), 256 threads; one float4 per thread per row-chunk.
__global__ __launch_bounds__(256)
void gather_kernel(const float* __restrict__ x, const int* __restrict__ perm,
                   float* __restrict__ comb, float* __restrict__ xm)
{
    const int p  = blockIdx.y;                       // permuted row index
    const int c4 = blockIdx.x * 256 + threadIdx.x;   // float4 column 0..1023
    const int src = perm[p];
    const float4 v = *(const float4*)(x + (size_t)src * 4096 + (size_t)c4 * 4);
    if (p < 2048) *(float4*)(comb + (size_t)p * 4096 + (size_t)c4 * 4) = v;
    else          *(float4*)(xm + (size_t)(p - 2048) * 4096 + (size_t)c4 * 4) = v;
}

// ---------------------------------------------------------------------------
// Tiled SGEMM: C[M,N] = A[M,K] @ op(B) (+ epilogue).
//   BT=true : B stored [N,K] row-major (C = A B^T)  -- all the W matrices
//   BT=false: B stored [K,N] row-major (C = A B)    -- modality_priors
// Tile 128x128xBK16, 256 threads, 8x8 accum per thread.
// EPI: 0 plain store; 1 relu(acc+bias); 3 acc+bias;
//      2 var/w epilogue (writes w to C and w,var to d_out sections);
//      5 x_reg epilogue (softplus regularizer, writes into comb bottom half).
// ---------------------------------------------------------------------------
template <int EPI, bool BT>
__global__ __launch_bounds__(256)
void gemm_kernel(const float* __restrict__ A, const float* __restrict__ Bm,
                 float* __restrict__ C, int M, int N, int K,
                 const float* __restrict__ bias,
                 const float* __restrict__ aux1,   // eps_w (EPI2) / eps_r (EPI5), global-row indexed
                 const float* __restrict__ aux2,   // mean_tmp (EPI5), branch-row indexed
                 const float* __restrict__ aux3,   // x_rec (EPI5), branch-row indexed
                 float* __restrict__ out1,         // d_out w section (EPI2)
                 float* __restrict__ out2,         // d_out var section (EPI2)
                 const int* __restrict__ perm)
{
    __shared__ float As[16][128];
    __shared__ float Bs[16][128];
    const int t    = threadIdx.x;
    const int row0 = blockIdx.y * 128;
    const int col0 = blockIdx.x * 128;
    const int tx   = t & 15;
    const int ty   = t >> 4;

    float acc[8][8];
#pragma unroll
    for (int i = 0; i < 8; ++i)
#pragma unroll
        for (int j = 0; j < 8; ++j) acc[i][j] = 0.f;

    for (int k0 = 0; k0 < K; k0 += 16) {
        // A tile 128x16, stored K-transposed into LDS.
#pragma unroll
        for (int jj = 0; jj < 2; ++jj) {
            int f = t + 256 * jj;          // float4 id 0..511
            int r = f >> 2;                // tile row 0..127
            int c = (f & 3) << 2;          // tile col 0,4,8,12
            float4 v = *(const float4*)(A + (size_t)(row0 + r) * K + (k0 + c));
            As[c + 0][r] = v.x; As[c + 1][r] = v.y;
            As[c + 2][r] = v.z; As[c + 3][r] = v.w;
        }
        if constexpr (BT) {
#pragma unroll
            for (int jj = 0; jj < 2; ++jj) {
                int f = t + 256 * jj;
                int r = f >> 2;            // n within tile
                int c = (f & 3) << 2;
                int gn = col0 + r;
                float4 v = make_float4(0.f, 0.f, 0.f, 0.f);
                if (gn < N)                // N=1000 tail guard (gemm7)
                    v = *(const float4*)(Bm + (size_t)gn * K + (k0 + c));
                Bs[c + 0][r] = v.x; Bs[c + 1][r] = v.y;
                Bs[c + 2][r] = v.z; Bs[c + 3][r] = v.w;
            }
        } else {
#pragma unroll
            for (int jj = 0; jj < 2; ++jj) {
                int f = t + 256 * jj;
                int r = f >> 5;            // k row 0..15 (32 float4 per row)
                int c = (f & 31) << 2;     // col 0..124
                float4 v = *(const float4*)(Bm + (size_t)(k0 + r) * N + (col0 + c));
                *(float4*)&Bs[r][c] = v;
            }
        }
        __syncthreads();
#pragma unroll
        for (int kk = 0; kk < 16; ++kk) {
            float a[8], b[8];
            *(float4*)&a[0] = *(const float4*)&As[kk][ty * 8];
            *(float4*)&a[4] = *(const float4*)&As[kk][ty * 8 + 4];
            *(float4*)&b[0] = *(const float4*)&Bs[kk][tx * 8];
            *(float4*)&b[4] = *(const float4*)&Bs[kk][tx * 8 + 4];
#pragma unroll
            for (int i = 0; i < 8; ++i)
#pragma unroll
                for (int j = 0; j < 8; ++j)
                    acc[i][j] = fmaf(a[i], b[j], acc[i][j]);
        }
        __syncthreads();
    }

    // Epilogue.
#pragma unroll
    for (int i = 0; i < 8; ++i) {
        const int gr = row0 + ty * 8 + i;
#pragma unroll
        for (int j = 0; j < 8; ++j) {
            const int gc = col0 + tx * 8 + j;
            if (gc >= N) continue;
            const float v = acc[i][j];
            if constexpr (EPI == 0) {
                C[(size_t)gr * N + gc] = v;
            } else if constexpr (EPI == 1) {
                C[(size_t)gr * N + gc] = fmaxf(v + bias[gc], 0.f);
            } else if constexpr (EPI == 3) {
                C[(size_t)gr * N + gc] = v + bias[gc];
            } else if constexpr (EPI == 2) {
                // var = exp(lv); w = 1 + sqrt(var)*eps_w[global_row]
                const int g = perm[2048 + gr];     // original (odd) row id
                const float var = expf(v + bias[gc]);
                const float w   = fmaf(sqrtf(var), aux1[(size_t)g * N + gc], 1.f);
                C[(size_t)gr * N + gc]    = w;     // w_m for gemm3
                out1[(size_t)gr * N + gc] = w;     // d_out: w[miss_idx]
                out2[(size_t)gr * N + gc] = var;   // d_out: var[miss_idx]
            } else if constexpr (EPI == 5) {
                // reg = mean + exp(0.5*lr)*eps_r; x_reg = x_rec*softplus(reg)
                const int g = perm[2048 + gr];
                const float sd = expf(0.5f * (v + bias[gc]));
                const float z  = fmaf(sd, aux1[(size_t)g * N + gc],
                                      aux2[(size_t)gr * N + gc]);
                // softplus = logaddexp(z, 0) (stable, matches jax.nn.softplus)
                const float sp = fmaxf(z, 0.f) + log1pf(expf(-fabsf(z)));
                C[(size_t)(2048 + gr) * N + gc] = aux3[(size_t)gr * N + gc] * sp;
            }
        }
    }
}

extern "C" void kernel_launch(void* const* d_in, const int* in_sizes, int n_in,
                              void* d_out, int out_size, void* d_ws, size_t ws_size,
                              hipStream_t stream)
{
    (void)in_sizes; (void)n_in; (void)out_size; (void)ws_size;

    const float* x      = (const float*)d_in[0];
    const int*   mm     = (const int*)  d_in[1];
    const float* priors = (const float*)d_in[2];
    const float* W1  = (const float*)d_in[3];
    const float* b1  = (const float*)d_in[4];
    const float* W2  = (const float*)d_in[5];
    const float* b2  = (const float*)d_in[6];
    const float* Wr1 = (const float*)d_in[7];
    const float* br1 = (const float*)d_in[8];
    const float* Wlv = (const float*)d_in[9];
    const float* blv = (const float*)d_in[10];
    const float* Wg1 = (const float*)d_in[11];
    const float* bg1 = (const float*)d_in[12];
    const float* Wm  = (const float*)d_in[13];
    const float* bm  = (const float*)d_in[14];
    const float* Wl  = (const float*)d_in[15];
    const float* bl  = (const float*)d_in[16];
    const float* eps_w = (const float*)d_in[17];
    const float* eps_r = (const float*)d_in[18];

    float* out        = (float*)d_out;
    float* out_logits = out;                              // 4096*1000
    float* out_w      = out + (size_t)4096 * 1000;        // 2048*2048
    float* out_var    = out_w + (size_t)2048 * 2048;      // 2048*2048

    // Workspace layout (floats), ~134 MB total:
    //   [0,32KB)          : perm (4096 ints)
    //   fb + 0   .. 8M    : x_m, later aliased by x_rec, later by h1[0:8M]
    //   fb + 8M  .. 16M   : h, later hr, later h1[8M:16M]
    //   fb + 16M .. 32M   : comb (permuted combined, 4096x4096)
    //     comb+8M..12M    : w_m (2048x2048) -- dead before gemm5a overwrites
    //     comb+8M..16M    : mean_tmp, then x_reg (bottom half of comb)
    int*   perm = (int*)d_ws;
    float* fb   = (float*)((char*)d_ws + 32768);
    const size_t M1 = 1024 * 1024;
    float* xm   = fb;
    float* hb   = fb + 8 * M1;
    float* h1   = fb;                 // 16M floats, alias after branch done
    float* comb = fb + 16 * M1;
    float* wb   = comb + 8 * M1;      // inside comb bottom half
    float* xrec = xm;                 // alias: x_m dead after gemm1
    float* mtmp = comb + (size_t)2048 * 4096;  // == comb+8M == bottom half

    perm_kernel<<<1, 1024, 0, stream>>>(mm, perm);
    gather_kernel<<<dim3(4, 4096), 256, 0, stream>>>(x, perm, comb, xm);

    // 1: h = relu(x_m @ Wr1^T + br1)            (2048x4096, K=4096)
    gemm_kernel<1, true><<<dim3(32, 16), 256, 0, stream>>>(
        xm, Wr1, hb, 2048, 4096, 4096, br1,
        nullptr, nullptr, nullptr, nullptr, nullptr, nullptr);
    // 2: var = exp(h @ Wlv^T + blv); w = 1+sqrt(var)*eps_w; emit outputs
    gemm_kernel<2, true><<<dim3(16, 16), 256, 0, stream>>>(
        hb, Wlv, wb, 2048, 2048, 4096, blv,
        eps_w, nullptr, nullptr, out_w, out_var, perm);
    // 3: x_rec = w @ priors (NN)                (2048x4096, K=2048)
    gemm_kernel<0, false><<<dim3(32, 16), 256, 0, stream>>>(
        wb, priors, xrec, 2048, 4096, 2048, nullptr,
        nullptr, nullptr, nullptr, nullptr, nullptr, nullptr);
    // 4: hr = relu(x_rec @ Wg1^T + bg1)
    gemm_kernel<1, true><<<dim3(32, 16), 256, 0, stream>>>(
        xrec, Wg1, hb, 2048, 4096, 4096, bg1,
        nullptr, nullptr, nullptr, nullptr, nullptr, nullptr);
    // 5a: mean_reg = hr @ Wm^T + bm  -> comb bottom half (temp)
    gemm_kernel<3, true><<<dim3(32, 16), 256, 0, stream>>>(
        hb, Wm, mtmp, 2048, 4096, 4096, bm,
        nullptr, nullptr, nullptr, nullptr, nullptr, nullptr);
    // 5b: lr = hr @ Wl^T + bl; x_reg = x_rec*softplus(mean+exp(.5lr)*eps_r)
    //     -> overwrites comb bottom half in place (read mean, write x_reg)
    gemm_kernel<5, true><<<dim3(32, 16), 256, 0, stream>>>(
        hb, Wl, comb, 2048, 4096, 4096, bl,
        eps_r, mtmp, xrec, nullptr, nullptr, perm);
    // 6: h1 = relu(comb @ W1^T + b1)            (4096x4096, K=4096)
    gemm_kernel<1, true><<<dim3(32, 32), 256, 0, stream>>>(
        comb, W1, h1, 4096, 4096, 4096, b1,
        nullptr, nullptr, nullptr, nullptr, nullptr, nullptr);
    // 7: logits = h1 @ W2^T + b2                (4096x1000, K=4096)
    gemm_kernel<3, true><<<dim3(8, 32), 256, 0, stream>>>(
        h1, W2, out_logits, 4096, 1000, 4096, b2,
        nullptr, nullptr, nullptr, nullptr, nullptr, nullptr);
}

// Round 2
// 2339.016 us; speedup vs baseline: 3.1200x; 3.1200x over previous
//
#include <hip/hip_runtime.h>
#include <cmath>
#include <cstddef>
#include <cstdint>

// ---------------------------------------------------------------------------
// Round 2: fp16 MFMA (v_mfma_f32_32x32x16_f16) for all 8 GEMMs.
// Masked VAE branch on 2048 rows; classifier on 4096 rows. 515 GFLOP total.
// Weights pre-converted fp32->fp16 each call (~150us); activations written
// fp16 directly by GEMM epilogues. fp32 accumulate throughout.
// XOR-swizzled LDS: global_load_lds lane-order == swizzled layout, and
// ds_read_b128 fragment reads hit 8 distinct bank-quads (8-cycle floor).
// ---------------------------------------------------------------------------

typedef _Float16 f16x8 __attribute__((ext_vector_type(8)));
typedef _Float16 f16x4 __attribute__((ext_vector_type(4)));
typedef float    f32x16 __attribute__((ext_vector_type(16)));

__device__ __forceinline__ void load_lds16(const _Float16* g, _Float16* l)
{
    __builtin_amdgcn_global_load_lds(
        (const __attribute__((address_space(1))) void*)g,
        (__attribute__((address_space(3))) void*)l, 16, 0, 0);
}

// Stable binary argsort of mask (mm%2): perm = [evens..., odds...].
__global__ __launch_bounds__(1024)
void perm_kernel(const int* __restrict__ mm, int* __restrict__ perm)
{
    __shared__ int sdata[1024];
    const int t = threadIdx.x;
    int m[4]; int cnt = 0;
#pragma unroll
    for (int j = 0; j < 4; ++j) { int i = t*4 + j; m[j] = mm[i] & 1; cnt += m[j]; }
    sdata[t] = cnt;
    __syncthreads();
    for (int off = 1; off < 1024; off <<= 1) {
        int v = (t >= off) ? sdata[t - off] : 0;
        __syncthreads();
        sdata[t] += v;
        __syncthreads();
    }
    const int n0 = 4096 - sdata[1023];
    int ones_before  = sdata[t] - cnt;
    int zeros_before = t*4 - ones_before;
#pragma unroll
    for (int j = 0; j < 4; ++j) {
        int i = t*4 + j;
        if (m[j]) perm[n0 + (ones_before++)] = i;
        else      perm[(zeros_before++)]     = i;
    }
}

// x fp32 -> comb16 top half (unmasked rows) and xm16 (masked rows), fp16.
__global__ __launch_bounds__(256)
void gather_kernel(const float* __restrict__ x, const int* __restrict__ perm,
                   _Float16* __restrict__ comb, _Float16* __restrict__ xm)
{
    const int p  = blockIdx.y;
    const int c4 = blockIdx.x * 256 + threadIdx.x;   // float4 col 0..1023
    const int src = perm[p];
    const float4 v = *(const float4*)(x + (size_t)src * 4096 + (size_t)c4 * 4);
    f16x4 h = { (_Float16)v.x, (_Float16)v.y, (_Float16)v.z, (_Float16)v.w };
    if (p < 2048) *(f16x4*)(comb + (size_t)p * 4096 + (size_t)c4 * 4) = h;
    else          *(f16x4*)(xm + (size_t)(p - 2048) * 4096 + (size_t)c4 * 4) = h;
}

// Flat fp32 -> fp16 convert, 4 elems/thread.
__global__ __launch_bounds__(256)
void cvt_kernel(const float* __restrict__ src, _Float16* __restrict__ dst, int n4)
{
    int i = blockIdx.x * 256 + threadIdx.x;
    if (i >= n4) return;
    float4 v = ((const float4*)src)[i];
    f16x4 h = { (_Float16)v.x, (_Float16)v.y, (_Float16)v.z, (_Float16)v.w };
    ((f16x4*)dst)[i] = h;
}

// W2 [1000,4096] fp32 -> [1024,4096] fp16, rows 1000..1023 zeroed.
__global__ __launch_bounds__(256)
void cvt_w2_kernel(const float* __restrict__ src, _Float16* __restrict__ dst)
{
    int i = blockIdx.x * 256 + threadIdx.x;      // float4 index, 1M total
    int row = (i * 4) >> 12;
    f16x4 h = { (_Float16)0.f, (_Float16)0.f, (_Float16)0.f, (_Float16)0.f };
    if (row < 1000) {
        float4 v = ((const float4*)src)[i];
        h = f16x4{ (_Float16)v.x, (_Float16)v.y, (_Float16)v.z, (_Float16)v.w };
    }
    ((f16x4*)dst)[i] = h;
}

// priors [2048,4096] fp32 -> priorsT [4096,2048] fp16 (tiled transpose).
__global__ __launch_bounds__(256)
void cvt_t_kernel(const float* __restrict__ src, _Float16* __restrict__ dst)
{
    __shared__ float t[32][33];
    const int tx = threadIdx.x, ty = threadIdx.y;
    const int c0 = blockIdx.x * 32, r0 = blockIdx.y * 32;
#pragma unroll
    for (int j = 0; j < 4; ++j)
        t[ty + 8*j][tx] = src[(size_t)(r0 + ty + 8*j) * 4096 + c0 + tx];
    __syncthreads();
#pragma unroll
    for (int j = 0; j < 4; ++j)
        dst[(size_t)(c0 + ty + 8*j) * 2048 + r0 + tx] = (_Float16)t[tx][ty + 8*j];
}

// ---------------------------------------------------------------------------
// fp16 MFMA GEMM: C = A[M,K] @ B[N,K]^T (+epilogue). BM=BN=128, BK=32,
// 128 threads = 2 waves; wave tile 128x64 = 4x2 of 32x32x16 MFMA tiles.
// EPI: 0 ->C16; 1 relu+bias->C16; 3 bias->C16; 7 bias->Cf (guard gc<Nc);
//      2 var/w epilogue; 5 softplus/x_reg epilogue (writes comb bottom half).
// ---------------------------------------------------------------------------
template <int EPI>
__global__ __launch_bounds__(128, 2)
void gemm16(const _Float16* __restrict__ A, const _Float16* __restrict__ B,
            _Float16* __restrict__ C16, float* __restrict__ Cf,
            int M, int N, int K, int Nc,
            const float* __restrict__ bias,
            const float* __restrict__ eps,       // eps_w (EPI2)/eps_r (EPI5)
            const _Float16* __restrict__ aux_m,  // mean_tmp fp16 (EPI5)
            const _Float16* __restrict__ aux_x,  // x_rec fp16 (EPI5)
            float* __restrict__ out1, float* __restrict__ out2,
            const int* __restrict__ perm)
{
    __shared__ _Float16 As[128 * 32];
    __shared__ _Float16 Bs[128 * 32];
    const int t    = threadIdx.x;
    const int lane = t & 63;
    const int wid  = t >> 6;            // 0..1
    const int row0 = blockIdx.y * 128;
    const int col0 = blockIdx.x * 128;

    f32x16 acc[4][2];
#pragma unroll
    for (int i = 0; i < 4; ++i)
#pragma unroll
        for (int j = 0; j < 2; ++j)
#pragma unroll
            for (int r = 0; r < 16; ++r) acc[i][j][r] = 0.f;

    // Staging addresses: each wave instruction covers 16 rows x 32 k (fp16).
    // LDS slot lane*16B == (r = base+lane>>2, chunk = lane&3); global chunk
    // is XOR-swizzled: c' = (lane&3) ^ (r&3).
    const _Float16* ap[4];
    const _Float16* bp[4];
    int loff[4];
#pragma unroll
    for (int i = 0; i < 4; ++i) {
        int r  = wid * 64 + i * 16 + (lane >> 2);
        int cc = (lane & 3) ^ (r & 3);
        ap[i]   = A + (size_t)(row0 + r) * K + cc * 8;
        bp[i]   = B + (size_t)(col0 + r) * K + cc * 8;
        loff[i] = (wid * 64 + i * 16) * 32;
    }

    for (int k0 = 0; k0 < K; k0 += 32) {
#pragma unroll
        for (int i = 0; i < 4; ++i) {
            load_lds16(ap[i], &As[loff[i]]);
            load_lds16(bp[i], &Bs[loff[i]]);
            ap[i] += 32; bp[i] += 32;
        }
        __syncthreads();
#pragma unroll
        for (int ks = 0; ks < 2; ++ks) {
            f16x8 af[4], bf[2];
#pragma unroll
            for (int ti = 0; ti < 4; ++ti) {
                int r = ti * 32 + (lane & 31);
                int c = (ks * 2 + (lane >> 5)) ^ (r & 3);
                af[ti] = *(const f16x8*)&As[r * 32 + c * 8];
            }
#pragma unroll
            for (int tj = 0; tj < 2; ++tj) {
                int n = wid * 64 + tj * 32 + (lane & 31);
                int c = (ks * 2 + (lane >> 5)) ^ (n & 3);
                bf[tj] = *(const f16x8*)&Bs[n * 32 + c * 8];
            }
#pragma unroll
            for (int ti = 0; ti < 4; ++ti)
#pragma unroll
                for (int tj = 0; tj < 2; ++tj)
                    acc[ti][tj] = __builtin_amdgcn_mfma_f32_32x32x16_f16(
                        af[ti], bf[tj], acc[ti][tj], 0, 0, 0);
        }
        __syncthreads();
    }

    // Epilogue. C/D layout (32x32): col = lane&31, row = (reg&3)+8*(reg>>2)+4*(lane>>5).
    const int ln = lane & 31;
    const int lh = lane >> 5;
#pragma unroll
    for (int ti = 0; ti < 4; ++ti) {
#pragma unroll
        for (int tj = 0; tj < 2; ++tj) {
            const int gc = col0 + wid * 64 + tj * 32 + ln;
#pragma unroll
            for (int reg = 0; reg < 16; ++reg) {
                const int gr = row0 + ti * 32 + (reg & 3) + 8 * (reg >> 2) + 4 * lh;
                const float v = acc[ti][tj][reg];
                if constexpr (EPI == 0) {
                    C16[(size_t)gr * N + gc] = (_Float16)v;
                } else if constexpr (EPI == 1) {
                    C16[(size_t)gr * N + gc] = (_Float16)fmaxf(v + bias[gc], 0.f);
                } else if constexpr (EPI == 3) {
                    C16[(size_t)gr * N + gc] = (_Float16)(v + bias[gc]);
                } else if constexpr (EPI == 7) {
                    if (gc < Nc) Cf[(size_t)gr * Nc + gc] = v + bias[gc];
                } else if constexpr (EPI == 2) {
                    const int g = perm[2048 + gr];
                    const float var = expf(v + bias[gc]);
                    const float w   = fmaf(sqrtf(var), eps[(size_t)g * N + gc], 1.f);
                    C16[(size_t)gr * N + gc]  = (_Float16)w;
                    out1[(size_t)gr * N + gc] = w;
                    out2[(size_t)gr * N + gc] = var;
                } else if constexpr (EPI == 5) {
                    const int g = perm[2048 + gr];
                    const float sd = expf(0.5f * (v + bias[gc]));
                    const float z  = fmaf(sd, eps[(size_t)g * N + gc],
                                          (float)aux_m[(size_t)gr * N + gc]);
                    const float sp = fmaxf(z, 0.f) + log1pf(expf(-fabsf(z)));
                    C16[(size_t)(2048 + gr) * N + gc] =
                        (_Float16)((float)aux_x[(size_t)gr * N + gc] * sp);
                }
            }
        }
    }
}

extern "C" void kernel_launch(void* const* d_in, const int* in_sizes, int n_in,
                              void* d_out, int out_size, void* d_ws, size_t ws_size,
                              hipStream_t stream)
{
    (void)in_sizes; (void)n_in; (void)out_size; (void)ws_size;

    const float* x      = (const float*)d_in[0];
    const int*   mm     = (const int*)  d_in[1];
    const float* priors = (const float*)d_in[2];
    const float* W1  = (const float*)d_in[3];
    const float* b1  = (const float*)d_in[4];
    const float* W2  = (const float*)d_in[5];
    const float* b2  = (const float*)d_in[6];
    const float* Wr1 = (const float*)d_in[7];
    const float* br1 = (const float*)d_in[8];
    const float* Wlv = (const float*)d_in[9];
    const float* blv = (const float*)d_in[10];
    const float* Wg1 = (const float*)d_in[11];
    const float* bg1 = (const float*)d_in[12];
    const float* Wm  = (const float*)d_in[13];
    const float* bm  = (const float*)d_in[14];
    const float* Wl  = (const float*)d_in[15];
    const float* bl  = (const float*)d_in[16];
    const float* eps_w = (const float*)d_in[17];
    const float* eps_r = (const float*)d_in[18];

    float* out        = (float*)d_out;
    float* out_logits = out;                           // 4096x1000
    float* out_w      = out + (size_t)4096 * 1000;     // 2048x2048
    float* out_var    = out_w + (size_t)2048 * 2048;   // 2048x2048

    // Workspace layout (~288 MB):
    int* perm = (int*)d_ws;
    char* base = (char*)d_ws + 32768;
    _Float16* wr1h  = (_Float16*)(base);                    // 32 MB
    _Float16* wlvh  = (_Float16*)(base + 33554432);         // 16 MB
    _Float16* priTh = (_Float16*)(base + 50331648);         // 16 MB [4096,2048]
    _Float16* wg1h  = (_Float16*)(base + 67108864);         // 32 MB
    _Float16* wmh   = (_Float16*)(base + 100663296);        // 32 MB
    _Float16* wlh   = (_Float16*)(base + 134217728);        // 32 MB
    _Float16* w1h   = (_Float16*)(base + 167772160);        // 32 MB
    _Float16* w2ph  = (_Float16*)(base + 201326592);        // 8 MB [1024,4096]
    char* acts = base + 209715200;
    _Float16* xm16   = (_Float16*)(acts);                   // 16 MB (xrec16 alias)
    _Float16* h16    = (_Float16*)(acts + 16777216);        // 16 MB (hr16 alias)
    _Float16* w16    = (_Float16*)(acts + 33554432);        //  8 MB
    _Float16* mtmp16 = (_Float16*)(acts + 41943040);        // 16 MB
    _Float16* comb16 = (_Float16*)(acts + 58720256);        // 32 MB
    _Float16* xrec16 = xm16;    // x_m dead after gemm1
    _Float16* hr16   = h16;     // h dead after gemm2
    _Float16* h1_16  = xm16;    // branch dead after gemm5b (32 MB over xm16+h16)

    perm_kernel<<<1, 1024, 0, stream>>>(mm, perm);

    // Weight conversions (fp32 -> fp16), ~600 MB HBM traffic total.
    cvt_kernel<<<16384, 256, 0, stream>>>(Wr1, wr1h, 4194304);
    cvt_kernel<<< 8192, 256, 0, stream>>>(Wlv, wlvh, 2097152);
    cvt_t_kernel<<<dim3(128, 64), dim3(32, 8), 0, stream>>>(priors, priTh);
    cvt_kernel<<<16384, 256, 0, stream>>>(Wg1, wg1h, 4194304);
    cvt_kernel<<<16384, 256, 0, stream>>>(Wm,  wmh,  4194304);
    cvt_kernel<<<16384, 256, 0, stream>>>(Wl,  wlh,  4194304);
    cvt_kernel<<<16384, 256, 0, stream>>>(W1,  w1h,  4194304);
    cvt_w2_kernel<<<4096, 256, 0, stream>>>(W2, w2ph);

    gather_kernel<<<dim3(4, 4096), 256, 0, stream>>>(x, perm, comb16, xm16);

    // 1: h = relu(x_m @ Wr1^T + br1)          [2048,4096] K=4096
    gemm16<1><<<dim3(32, 16), 128, 0, stream>>>(
        xm16, wr1h, h16, nullptr, 2048, 4096, 4096, 4096, br1,
        nullptr, nullptr, nullptr, nullptr, nullptr, nullptr);
    // 2: var/w epilogue                        [2048,2048] K=4096
    gemm16<2><<<dim3(16, 16), 128, 0, stream>>>(
        h16, wlvh, w16, nullptr, 2048, 2048, 4096, 2048, blv,
        eps_w, nullptr, nullptr, out_w, out_var, perm);
    // 3: x_rec = w @ priors                    [2048,4096] K=2048
    gemm16<0><<<dim3(32, 16), 128, 0, stream>>>(
        w16, priTh, xrec16, nullptr, 2048, 4096, 2048, 4096, nullptr,
        nullptr, nullptr, nullptr, nullptr, nullptr, nullptr);
    // 4: hr = relu(x_rec @ Wg1^T + bg1)
    gemm16<1><<<dim3(32, 16), 128, 0, stream>>>(
        xrec16, wg1h, hr16, nullptr, 2048, 4096, 4096, 4096, bg1,
        nullptr, nullptr, nullptr, nullptr, nullptr, nullptr);
    // 5a: mean_reg -> mtmp16
    gemm16<3><<<dim3(32, 16), 128, 0, stream>>>(
        hr16, wmh, mtmp16, nullptr, 2048, 4096, 4096, 4096, bm,
        nullptr, nullptr, nullptr, nullptr, nullptr, nullptr);
    // 5b: x_reg = x_rec * softplus(mean + exp(0.5*lr)*eps_r) -> comb bottom
    gemm16<5><<<dim3(32, 16), 128, 0, stream>>>(
        hr16, wlh, comb16, nullptr, 2048, 4096, 4096, 4096, bl,
        eps_r, mtmp16, xrec16, nullptr, nullptr, perm);
    // 6: h1 = relu(comb @ W1^T + b1)           [4096,4096] K=4096
    gemm16<1><<<dim3(32, 32), 128, 0, stream>>>(
        comb16, w1h, h1_16, nullptr, 4096, 4096, 4096, 4096, b1,
        nullptr, nullptr, nullptr, nullptr, nullptr, nullptr);
    // 7: logits = h1 @ W2^T + b2 (fp32 out, guard gc<1000)
    gemm16<7><<<dim3(8, 32), 128, 0, stream>>>(
        h1_16, w2ph, nullptr, out_logits, 4096, 1024, 4096, 1000, b2,
        nullptr, nullptr, nullptr, nullptr, nullptr, nullptr);
}